// Round 8
// baseline (529.670 us; speedup 1.0000x reference)
//
#include <hip/hip_runtime.h>
#include <hip/hip_bf16.h>

typedef __attribute__((ext_vector_type(8))) short bf16x8;
typedef __attribute__((ext_vector_type(4))) short bf16x4;
typedef __attribute__((ext_vector_type(4))) float f32x4;
typedef __attribute__((ext_vector_type(16))) float f32x16;
typedef __hip_bfloat16 bf16;
typedef unsigned short u16;

#define B_ 4
#define S_ 2048
#define D_ 1024
#define F_ 4096
#define H_ 16
#define MROWS 8192   // B_*S_
// 1/sqrt(dk) * log2(e), folded into the q-slice of the QKV GEMM epilogue
#define QSCALE 0.18033688011116012f

// ---------------- helpers ----------------
// pack 2 f32 -> 2 bf16 (round-half-up): 2 adds + 1 v_perm
__device__ __forceinline__ unsigned pkbf(float lo, float hi){
  union{float f; unsigned u;} a, b; a.f = lo; b.f = hi;
  return __builtin_amdgcn_perm(b.u + 0x8000u, a.u + 0x8000u, 0x07060302);
}
// single f32 -> bf16 bits (round-half-up): 2 VALU
__device__ __forceinline__ u16 bfrnd(float f){
  union{float ff; unsigned u;} c; c.ff = f;
  return (u16)((c.u + 0x8000u) >> 16);
}
// async global->LDS, 16B per lane; LDS dest = wave-uniform base + lane*16
__device__ __forceinline__ void gll16(const bf16* gp, u16* lp){
  __builtin_amdgcn_global_load_lds(
      (const __attribute__((address_space(1))) void*)gp,
      (__attribute__((address_space(3))) void*)lp, 16, 0, 0);
}

// ---------------- fused prep: 6 weight transposes + bias concat, ONE launch ----------------
// transpose semantics: W[K][N] f32 -> WT[N][K] bf16
struct PrepArgs { const float* w[6]; const float* b[3]; };
__global__ __launch_bounds__(256) void prep(
    PrepArgs pa, bf16* __restrict__ wqkvoT, bf16* __restrict__ w1T,
    bf16* __restrict__ w2T, float* __restrict__ bqkv)
{
  __shared__ float tl[32][33];
  const int bid = blockIdx.x, tid = threadIdx.x;
  const int x = tid&31, y = tid>>5;
  if (bid < 12288) {
    const float* W; bf16* dst; int K, N, nb, kb;
    if (bid < 4096)      { int wi=bid>>10, t=bid&1023; W=pa.w[wi]; dst=wqkvoT+(size_t)wi*1048576; K=1024; N=1024; nb=t&31;  kb=t>>5; }
    else if (bid < 8192) { int t=bid-4096;             W=pa.w[4];  dst=w1T;  K=1024; N=4096; nb=t&127; kb=t>>7; }
    else                 { int t=bid-8192;             W=pa.w[5];  dst=w2T;  K=4096; N=1024; nb=t&31;  kb=t>>5; }
    const int n0=nb*32, k0=kb*32;
    #pragma unroll
    for (int i=0;i<32;i+=8)
      tl[y+i][x] = W[(size_t)(k0+y+i)*N + n0+x];
    __syncthreads();
    #pragma unroll
    for (int i=0;i<32;i+=8)
      dst[(size_t)(n0+y+i)*K + k0+x] = __float2bfloat16(tl[x][y+i]);
  } else {
    for (int i=tid; i<3072; i+=256) bqkv[i] = pa.b[i>>10][i&1023];
  }
}

// ---------------- V transpose: qkv v-slice -> vT[bh][d][s] ----------------
__global__ __launch_bounds__(256) void v_transpose(
    const bf16* __restrict__ qkv, bf16* __restrict__ vT)
{
  __shared__ u16 tile[64*65];   // pitch 65 (odd) spreads banks for the column gather
  const int bh = blockIdx.y, b = bh>>4, h = bh&15;
  const int s0 = blockIdx.x*64;
  const int tid = threadIdx.x;
  const bf16* src = qkv + (size_t)(b*S_ + s0)*3072 + 2048 + h*64;
  #pragma unroll
  for (int i=0;i<2;i++){
    int idx = i*256 + tid;
    int r = idx>>3, sg = idx&7;
    uint4 v = *reinterpret_cast<const uint4*>(src + (size_t)r*3072 + sg*8);
    const u16* e = (const u16*)&v;
    #pragma unroll
    for (int j=0;j<8;j++) tile[r*65 + sg*8 + j] = e[j];
  }
  __syncthreads();
  bf16* dst = vT + (size_t)bh*64*S_ + s0;
  #pragma unroll
  for (int i=0;i<2;i++){
    int idx = i*256 + tid;
    int d = idx>>3, sg = idx&7;
    u16 tmp[8];
    #pragma unroll
    for (int j=0;j<8;j++) tmp[j] = tile[(sg*8+j)*65 + d];
    *reinterpret_cast<uint4*>(dst + (size_t)d*S_ + sg*8) = *reinterpret_cast<uint4*>(tmp);
  }
}

// ---------------- layernorm (torch-faithful: ddof=1, eps added to std) ----------------
__device__ __forceinline__ float block_reduce_256(float v, float* sbuf){
  #pragma unroll
  for (int o=32;o>0;o>>=1) v += __shfl_down(v, o);
  int wave = threadIdx.x>>6;
  if ((threadIdx.x&63)==0) sbuf[wave] = v;
  __syncthreads();
  float r = sbuf[0]+sbuf[1]+sbuf[2]+sbuf[3];
  __syncthreads();
  return r;
}

__global__ __launch_bounds__(256) void ln_fwd(
    const float* __restrict__ x, const float* __restrict__ alpha,
    const float* __restrict__ beta, bf16* __restrict__ out)
{
  __shared__ float sbuf[4];
  int row = blockIdx.x, tid = threadIdx.x;
  const float4* xr = reinterpret_cast<const float4*>(x + (size_t)row*D_);
  float4 v = xr[tid];
  float sum = block_reduce_256(v.x+v.y+v.z+v.w, sbuf);
  float mean = sum * (1.0f/1024.0f);
  float dx0=v.x-mean, dx1=v.y-mean, dx2=v.z-mean, dx3=v.w-mean;
  float ssq = block_reduce_256(dx0*dx0+dx1*dx1+dx2*dx2+dx3*dx3, sbuf);
  float std_ = sqrtf(ssq * (1.0f/1023.0f));        // ddof=1
  float inv = 1.0f/(std_ + 1e-6f);                 // eps added to std
  const float4* ar = reinterpret_cast<const float4*>(alpha);
  const float4* br = reinterpret_cast<const float4*>(beta);
  float4 a = ar[tid], bb = br[tid];
  unsigned* o = reinterpret_cast<unsigned*>(out + (size_t)row*D_);
  o[tid*2+0] = pkbf(a.x*dx0*inv + bb.x, a.y*dx1*inv + bb.y);
  o[tid*2+1] = pkbf(a.z*dx2*inv + bb.z, a.w*dx3*inv + bb.w);
}

// ---------------- GEMM: 512 threads, 128x128 tile, 8 waves of 64x32 (legacy fallback) ----------------
template<int EPI>
__global__ __launch_bounds__(512) void gemm_bt(
    const bf16* __restrict__ A, const bf16* __restrict__ BT,
    const float* __restrict__ bias, const float* __restrict__ res,
    void* __restrict__ out, int M, int N, int K)
{
  __shared__ __align__(16) u16 As[128*32];
  __shared__ __align__(16) u16 Bs[128*32];
  const int tid = threadIdx.x;
  const int m0 = blockIdx.x*128, n0 = blockIdx.y*128;
  const int wave = tid>>6, lane = tid&63;
  const int wm = (wave>>2)*64, wn = (wave&3)*32;
  const int lrow = lane&15, quad = lane>>4;
  const int srow = wave*16 + (lane>>2);
  const int sseg = lane&3;
  const bf16* apg = A  + (size_t)(m0+srow)*K + sseg*8;
  const bf16* bpg = BT + (size_t)(n0+srow)*K + sseg*8;
  u16* asd = &As[wave*512];
  u16* bsd = &Bs[wave*512];

  f32x4 acc[4][2];
  #pragma unroll
  for (int i=0;i<4;i++)
    #pragma unroll
    for (int j=0;j<2;j++) acc[i][j] = (f32x4){0.f,0.f,0.f,0.f};

  for (int k0=0; k0<K; k0+=32) {
    gll16(apg + k0, asd);
    gll16(bpg + k0, bsd);
    __syncthreads();
    bf16x8 a[4], b[2];
    #pragma unroll
    for (int t=0;t<4;t++)
      a[t] = *reinterpret_cast<const bf16x8*>(&As[(wm + t*16 + lrow)*32 + quad*8]);
    #pragma unroll
    for (int t=0;t<2;t++)
      b[t] = *reinterpret_cast<const bf16x8*>(&Bs[(wn + t*16 + lrow)*32 + quad*8]);
    #pragma unroll
    for (int mt=0;mt<4;mt++)
      #pragma unroll
      for (int nt=0;nt<2;nt++)
        acc[mt][nt] = __builtin_amdgcn_mfma_f32_16x16x32_bf16(a[mt], b[nt], acc[mt][nt], 0,0,0);
    __syncthreads();
  }

  #pragma unroll
  for (int mt=0;mt<4;mt++){
    #pragma unroll
    for (int nt=0;nt<2;nt++){
      int col = n0 + wn + nt*16 + lrow;
      float bv = bias[col];
      float sc = (EPI == 3 && col < 1024) ? QSCALE : 1.0f;
      #pragma unroll
      for (int r=0;r<4;r++){
        int row = m0 + wm + mt*16 + quad*4 + r;
        size_t idx = (size_t)row*N + col;
        float val = acc[mt][nt][r] + bv;
        if (EPI == 1) val = fmaxf(val, 0.0f);
        if (EPI == 3) val *= sc;
        if (EPI == 2) {
          ((float*)out)[idx] = val + res[idx];
        } else {
          ((u16*)out)[idx] = bfrnd(val);
        }
      }
    }
  }
}

// ---------------- GEMM 256x256, BK=64, 8-phase pipelined (m201-style template) ----------------
#define LA256(bu,hf) (lds + (((bu)*2+0)*2+(hf))*8192)
#define LB256(bu,hf) (lds + (((bu)*2+1)*2+(hf))*8192)

__device__ __forceinline__ bf16x8 ldfrag(const u16* base, int row, int chunk){
  int pc = chunk ^ (row & 7);                       // T2 swizzle on read
  return *reinterpret_cast<const bf16x8*>(base + row*64 + pc*8);
}

__device__ __forceinline__ void stage_half256(const bf16* __restrict__ src, int K,
                                              u16* lbase, int wave, int lane){
  #pragma unroll
  for (int i=0;i<2;i++){
    int q = i*512 + wave*64 + lane;                 // physical 16B chunk index
    int row = q>>3;
    int seg = (q&7) ^ (row&7);                      // inverse swizzle on global source
    gll16(src + (size_t)row*K + seg*8, lbase + (i*512 + wave*64)*8);
  }
}

template<int RH, int KS, bool RB, typename STG, typename TAIL>
__device__ __forceinline__ void gphase(const u16* pa, const u16* pb, int bcol,
    int lr, int quad, bf16x8 (&b)[4][2], f32x4 (&acc)[8][4], STG stg, TAIL tail)
{
  bf16x8 a_[4];
  #pragma unroll
  for (int ar=0; ar<4; ar++)
    a_[ar] = ldfrag(pa, RH*64 + ar*16 + lr, KS*4 + quad);
  if constexpr (RB){
    #pragma unroll
    for (int cb=0; cb<4; cb++){
      b[cb][0] = ldfrag(pb, bcol + cb*16 + lr, quad);
      b[cb][1] = ldfrag(pb, bcol + cb*16 + lr, 4 + quad);
    }
  }
  stg();
  __builtin_amdgcn_s_barrier();
  asm volatile("s_waitcnt lgkmcnt(0)" ::: "memory");
  __builtin_amdgcn_sched_barrier(0);                // rule #18: keep MFMAs below the wait
  __builtin_amdgcn_s_setprio(1);
  #pragma unroll
  for (int ar=0; ar<4; ar++)
    #pragma unroll
    for (int cb=0; cb<4; cb++)
      acc[RH*4+ar][cb] = __builtin_amdgcn_mfma_f32_16x16x32_bf16(a_[ar], b[cb][KS], acc[RH*4+ar][cb], 0,0,0);
  __builtin_amdgcn_s_setprio(0);
  tail();
  __builtin_amdgcn_s_barrier();
}

// EPI: 1=bf16+ReLU (FFN1), 3=bf16 with cols<1024 scaled by QSCALE (QKV). M fixed = MROWS.
template<int EPI>
__global__ __launch_bounds__(512) void gemm256(
    const bf16* __restrict__ A, const bf16* __restrict__ BT,
    const float* __restrict__ bias, bf16* __restrict__ out, int N, int K)
{
  __shared__ __align__(16) u16 lds[65536];          // 131072 B static (gfx950: 160 KiB LDS)
  const int tid = threadIdx.x, wave = tid>>6, lane = tid&63;
  const int wr = wave>>2, wc = wave&3;              // 2M x 4N wave grid
  const int lr = lane&15, quad = lane>>4;
  const int gx = gridDim.x;
  const int nwg = gx*gridDim.y;
  int flat = blockIdx.y*gx + blockIdx.x;
  int cpx = nwg>>3;
  int swz = (flat&7)*cpx + (flat>>3);
  const int m0 = (swz % gx)*256, n0 = (swz / gx)*256;
  const int T = K>>6;

  const bf16* Ag = A  + (size_t)m0*K;
  const bf16* Bg = BT + (size_t)n0*K;
  const int bcol = (wc&1)*64;

  f32x4 acc[8][4];
  #pragma unroll
  for (int i=0;i<8;i++)
    #pragma unroll
    for (int j=0;j<4;j++) acc[i][j] = (f32x4){0.f,0.f,0.f,0.f};

  // prologue: tile0 (4 halves) + B halves of tile1; allow B(1) in flight
  stage_half256(Ag,                       K, LA256(0,0), wave, lane);
  stage_half256(Ag + (size_t)128*K,       K, LA256(0,1), wave, lane);
  stage_half256(Bg,                       K, LB256(0,0), wave, lane);
  stage_half256(Bg + (size_t)128*K,       K, LB256(0,1), wave, lane);
  stage_half256(Bg + 64,                  K, LB256(1,0), wave, lane);
  stage_half256(Bg + (size_t)128*K + 64,  K, LB256(1,1), wave, lane);
  asm volatile("s_waitcnt vmcnt(4)" ::: "memory");
  __builtin_amdgcn_s_barrier();

  for (int t=0; t<T; ++t){
    const int bu = t&1, nbu = bu^1;
    const u16* pa = LA256(bu, wr);
    const u16* pb = LB256(bu, wc>>1);
    const size_t ktA = (size_t)((t+1 < T) ? t+1 : T-1)*64;   // clamp keeps vmcnt counts uniform
    const size_t ktB = (size_t)((t+2 < T) ? t+2 : T-1)*64;
    bf16x8 b[4][2];
    gphase<0,0,true >(pa, pb, bcol, lr, quad, b, acc,
        [&]{ stage_half256(Ag + ktA,                 K, LA256(nbu,0), wave, lane); }, [&]{});
    gphase<1,0,false>(pa, pb, bcol, lr, quad, b, acc,
        [&]{ stage_half256(Ag + (size_t)128*K + ktA, K, LA256(nbu,1), wave, lane); }, [&]{});
    gphase<0,1,false>(pa, pb, bcol, lr, quad, b, acc,
        [&]{ stage_half256(Bg + ktB,                 K, LB256(bu,0),  wave, lane); }, [&]{});
    gphase<1,1,false>(pa, pb, bcol, lr, quad, b, acc,
        [&]{ stage_half256(Bg + (size_t)128*K + ktB, K, LB256(bu,1),  wave, lane); },
        [&]{ asm volatile("s_waitcnt vmcnt(4)" ::: "memory"); });
  }

  // epilogue
  #pragma unroll
  for (int mi=0; mi<8; mi++){
    const int row0 = m0 + wr*128 + (mi>>2)*64 + (mi&3)*16 + quad*4;
    #pragma unroll
    for (int cb=0; cb<4; cb++){
      const int col = n0 + wc*64 + cb*16 + lr;
      float bv = bias[col];
      float sc = (EPI==3 && col < 1024) ? QSCALE : 1.0f;
      #pragma unroll
      for (int r=0; r<4; r++){
        float val = acc[mi][cb][r] + bv;
        if (EPI == 1) val = fmaxf(val, 0.0f);
        if (EPI == 3) val *= sc;
        ((u16*)out)[(size_t)(row0+r)*N + col] = bfrnd(val);
      }
    }
  }
}

// ---------------- GEMM 256x128, BK=64, 8-phase, f32+residual epilogue (Wo / FFN2) ----------------
#define LA2(bu,hf) (lds2 + ((bu)*3+(hf))*8192)
#define LB2(bu)    (lds2 + ((bu)*3+2)*8192)

template<int RH, int KS, bool RB, typename STG, typename TAIL>
__device__ __forceinline__ void gphase2(const u16* pa, const u16* pb, int bcol,
    int lr, int quad, bf16x8 (&b)[2][2], f32x4 (&acc)[8][2], STG stg, TAIL tail)
{
  bf16x8 a_[4];
  #pragma unroll
  for (int ar=0; ar<4; ar++)
    a_[ar] = ldfrag(pa, RH*64 + ar*16 + lr, KS*4 + quad);
  if constexpr (RB){
    #pragma unroll
    for (int cb=0; cb<2; cb++){
      b[cb][0] = ldfrag(pb, bcol + cb*16 + lr, quad);
      b[cb][1] = ldfrag(pb, bcol + cb*16 + lr, 4 + quad);
    }
  }
  stg();
  __builtin_amdgcn_s_barrier();
  asm volatile("s_waitcnt lgkmcnt(0)" ::: "memory");
  __builtin_amdgcn_sched_barrier(0);
  __builtin_amdgcn_s_setprio(1);
  #pragma unroll
  for (int ar=0; ar<4; ar++)
    #pragma unroll
    for (int cb=0; cb<2; cb++)
      acc[RH*4+ar][cb] = __builtin_amdgcn_mfma_f32_16x16x32_bf16(a_[ar], b[cb][KS], acc[RH*4+ar][cb], 0,0,0);
  __builtin_amdgcn_s_setprio(0);
  tail();
  __builtin_amdgcn_s_barrier();
}

__global__ __launch_bounds__(512) void gemm256r(
    const bf16* __restrict__ A, const bf16* __restrict__ BT,
    const float* __restrict__ bias, const float* __restrict__ res,
    float* __restrict__ out, int N, int K)
{
  __shared__ __align__(16) u16 lds2[49152];         // 96 KiB static
  const int tid = threadIdx.x, wave = tid>>6, lane = tid&63;
  const int wr = wave>>2, wc = wave&3;              // 2M x 4N wave grid
  const int lr = lane&15, quad = lane>>4;
  const int gx = gridDim.x;
  const int nwg = gx*gridDim.y;
  int flat = blockIdx.y*gx + blockIdx.x;
  int cpx = nwg>>3;
  int swz = (flat&7)*cpx + (flat>>3);
  const int m0 = (swz % gx)*256, n0 = (swz / gx)*128;
  const int T = K>>6;

  const bf16* Ag = A  + (size_t)m0*K;
  const bf16* Bg = BT + (size_t)n0*K;
  const int bcol = wc*32;

  f32x4 acc[8][2];
  #pragma unroll
  for (int i=0;i<8;i++)
    #pragma unroll
    for (int j=0;j<2;j++) acc[i][j] = (f32x4){0.f,0.f,0.f,0.f};

  // prologue: A(0) both halves, B(0), B(1); leave B(1) in flight
  stage_half256(Ag,                 K, LA2(0,0), wave, lane);
  stage_half256(Ag + (size_t)128*K, K, LA2(0,1), wave, lane);
  stage_half256(Bg,                 K, LB2(0),   wave, lane);
  stage_half256(Bg + 64,            K, LB2(1),   wave, lane);
  asm volatile("s_waitcnt vmcnt(2)" ::: "memory");
  __builtin_amdgcn_s_barrier();

  for (int t=0; t<T; ++t){
    const int bu = t&1, nbu = bu^1;
    const u16* pa = LA2(bu, wr);
    const u16* pb = LB2(bu);
    const size_t ktA = (size_t)((t+1 < T) ? t+1 : T-1)*64;
    const size_t ktB = (size_t)((t+2 < T) ? t+2 : T-1)*64;
    bf16x8 b[2][2];
    gphase2<0,0,true >(pa, pb, bcol, lr, quad, b, acc,
        [&]{ stage_half256(Ag + ktA,                 K, LA2(nbu,0), wave, lane); }, [&]{});
    gphase2<1,0,false>(pa, pb, bcol, lr, quad, b, acc,
        [&]{ stage_half256(Ag + (size_t)128*K + ktA, K, LA2(nbu,1), wave, lane); }, [&]{});
    gphase2<0,1,false>(pa, pb, bcol, lr, quad, b, acc,
        [&]{ stage_half256(Bg + ktB,                 K, LB2(bu),    wave, lane); }, [&]{});
    gphase2<1,1,false>(pa, pb, bcol, lr, quad, b, acc,
        [&]{}, [&]{ asm volatile("s_waitcnt vmcnt(2)" ::: "memory"); });
  }

  // epilogue: f32 + bias + residual
  #pragma unroll
  for (int mi=0; mi<8; mi++){
    const int row0 = m0 + wr*128 + (mi>>2)*64 + (mi&3)*16 + quad*4;
    #pragma unroll
    for (int cb=0; cb<2; cb++){
      const int col = n0 + bcol + cb*16 + lr;
      float bv = bias[col];
      #pragma unroll
      for (int r=0; r<4; r++){
        size_t idx = (size_t)(row0+r)*N + col;
        out[idx] = acc[mi][cb][r] + bv + res[idx];
      }
    }
  }
}

// ---------------- MFMA flash attention: 32x32-shape rewrite ----------------
// All matrix work on full-rate v_mfma_f32_32x32x16_bf16 (the old PV/l used half-rate
// K=16 16x16 legacy MFMA — ~55% of matrix-pipe cycles at half throughput).
// S^T = K·Q^T as 2x (32key x 32q) tiles; C-layout (m74/m101): col=lane&31=q,
// row=(reg&3)+8*(reg>>2)+4*(lane>>5). Each lane's 16 regs are 16 keys of ITS OWN q ->
// l-sum is 32 VALU adds (bf16-rounded for num/denom consistency) + one epilogue shfl.
// PV B-frag (8 keys/lane) = own 4-key chunk + partner half's chunk via __shfl_xor(.,32)
// (partner lane l^32 has the same q) + cndmask -- no LDS round-trip, no repack.
// Ks/Vt staging identical to the proven round-0 kernel.
#define KP 72   // LDS pitch: 144B rows, 16B-aligned for b128

__global__ __launch_bounds__(512,4) void flash_attn_mfma(
    const bf16* __restrict__ qkv, const bf16* __restrict__ vT,
    const int* __restrict__ mask, bf16* __restrict__ ctx)
{
  __shared__ __align__(16) u16 Ks[64*KP];       // K[key][d]
  __shared__ __align__(16) u16 Vt[64*KP];       // V^T[d][key]
  __shared__ __align__(16) float Mb[64];        // mask bias (slow path only)

  const int b = blockIdx.z, head = blockIdx.y, qt = blockIdx.x;
  const int tid = threadIdx.x, wave = tid>>6, lane = tid&63;
  const int lq = lane&31, hv = lane>>5;         // lane's q-column, half index
  const int qbase = qt*256 + wave*32;           // 32 q-rows per wave

  const bf16* base = qkv + (size_t)b*S_*3072 + head*64;
  const bf16* vtb  = vT + (size_t)(b*H_+head)*64*S_;
  const int*  mrow = mask + b*S_;

  // Q fragments (B-operand of 32x32x16 S^T mfma): lane lq owns q-row,
  // d-chunk i covers d = i*16 + hv*8 .. +7
  bf16x8 qf[4];
  {
    const bf16* qp = base + (size_t)(qbase + lq)*3072 + hv*8;
    #pragma unroll
    for (int i=0;i<4;i++)
      qf[i] = *reinterpret_cast<const bf16x8*>(qp + i*16);
  }

  f32x16 actx[2];                                // [dt] : ctx^T[d=dt*32+row(reg,hv)][q=lq]
  #pragma unroll
  for (int dt=0;dt<2;dt++)
    #pragma unroll
    for (int i=0;i<16;i++) actx[dt][i] = 0.f;
  float l_run = 0.f;

  const int sr = tid>>3, sg = tid&7;

  for (int kt=0; kt<S_; kt+=64){
    *reinterpret_cast<uint4*>(&Ks[sr*KP + sg*8]) =
      *reinterpret_cast<const uint4*>(base + 1024 + (size_t)(kt+sr)*3072 + sg*8);
    *reinterpret_cast<uint4*>(&Vt[sr*KP + sg*8]) =
      *reinterpret_cast<const uint4*>(vtb + (size_t)sr*S_ + kt + sg*8);
    if (tid < 64) Mb[tid] = (mrow[kt+tid]==0) ? -2e9f : 0.0f;
    unsigned long long bal = __ballot(mrow[kt + lane] == 0);
    __syncthreads();

    #pragma unroll
    for (int ks=0; ks<2; ks++){
      // ---- S^T tile (32 keys x 32 q): 4 MFMAs over D=64 ----
      f32x16 s;
      #pragma unroll
      for (int i=0;i<16;i++) s[i] = 0.f;
      #pragma unroll
      for (int i=0;i<4;i++){
        bf16x8 kf = *reinterpret_cast<const bf16x8*>(&Ks[(ks*32+lq)*KP + i*16 + hv*8]);
        s = __builtin_amdgcn_mfma_f32_32x32x16_bf16(kf, qf[i], s, 0,0,0);
      }
      // ---- exp2 (+mask bias), bf16-round, pack chunks, l-sum ----
      uint2 ch[4];
      #pragma unroll
      for (int g=0; g<4; g++){
        float e0,e1,e2,e3;
        if (bal == 0ULL){
          e0 = __builtin_amdgcn_exp2f(s[4*g+0]);
          e1 = __builtin_amdgcn_exp2f(s[4*g+1]);
          e2 = __builtin_amdgcn_exp2f(s[4*g+2]);
          e3 = __builtin_amdgcn_exp2f(s[4*g+3]);
        } else {
          float4 mb = *reinterpret_cast<const float4*>(&Mb[ks*32 + g*8 + hv*4]);
          e0 = __builtin_amdgcn_exp2f(s[4*g+0] + mb.x);
          e1 = __builtin_amdgcn_exp2f(s[4*g+1] + mb.y);
          e2 = __builtin_amdgcn_exp2f(s[4*g+2] + mb.z);
          e3 = __builtin_amdgcn_exp2f(s[4*g+3] + mb.w);
        }
        union{float f; unsigned u;} c0,c1,c2,c3;
        c0.f = e0; c1.f = e1; c2.f = e2; c3.f = e3;
        unsigned u0 = c0.u + 0x8000u, u1 = c1.u + 0x8000u;
        unsigned u2 = c2.u + 0x8000u, u3 = c3.u + 0x8000u;
        // l-sum from bf16-ROUNDED values (matches PV numerator rounding)
        union{unsigned u; float f;} r0,r1,r2,r3;
        r0.u = u0 & 0xffff0000u; r1.u = u1 & 0xffff0000u;
        r2.u = u2 & 0xffff0000u; r3.u = u3 & 0xffff0000u;
        l_run += (r0.f + r1.f) + (r2.f + r3.f);
        ch[g].x = __builtin_amdgcn_perm(u1, u0, 0x07060302);
        ch[g].y = __builtin_amdgcn_perm(u3, u2, 0x07060302);
      }
      // partner half's chunks (lane l^32 has same q)
      uint2 sw[4];
      #pragma unroll
      for (int g=0; g<4; g++){
        sw[g].x = __shfl_xor((int)ch[g].x, 32);
        sw[g].y = __shfl_xor((int)ch[g].y, 32);
      }
      // ---- PV: 2 k-steps of 16 keys x 2 d-tiles ----
      #pragma unroll
      for (int m=0; m<2; m++){
        union{unsigned u[4]; bf16x8 v;} fb;
        fb.u[0] = hv ? sw[2*m+1].x : ch[2*m].x;
        fb.u[1] = hv ? sw[2*m+1].y : ch[2*m].y;
        fb.u[2] = hv ? ch[2*m+1].x : sw[2*m].x;
        fb.u[3] = hv ? ch[2*m+1].y : sw[2*m].y;
        #pragma unroll
        for (int dt=0; dt<2; dt++){
          bf16x8 vf = *reinterpret_cast<const bf16x8*>(
              &Vt[(dt*32+lq)*KP + ks*32 + m*16 + hv*8]);
          actx[dt] = __builtin_amdgcn_mfma_f32_32x32x16_bf16(vf, fb.v, actx[dt], 0,0,0);
        }
      }
    }
    __syncthreads();
  }

  // ---- epilogue: complete l across halves, normalize, 8B stores ----
  float lfull = l_run + __shfl_xor(l_run, 32);
  float inv = 1.0f/lfull;
  int q = qbase + lq;
  bf16* op = ctx + (size_t)(b*S_+q)*D_ + head*64;
  #pragma unroll
  for (int dt=0; dt<2; dt++){
    #pragma unroll
    for (int g=0; g<4; g++){
      uint2 o;
      o.x = pkbf(actx[dt][4*g+0]*inv, actx[dt][4*g+1]*inv);
      o.y = pkbf(actx[dt][4*g+2]*inv, actx[dt][4*g+3]*inv);
      *reinterpret_cast<uint2*>(op + dt*32 + g*8 + hv*4) = o;
    }
  }
}

// ---------------- launch ----------------
extern "C" void kernel_launch(void* const* d_in, const int* in_sizes, int n_in,
                              void* d_out, int out_size, void* d_ws, size_t ws_size,
                              hipStream_t stream) {
  const float* x    = (const float*)d_in[0];
  const int*   mask = (const int*)  d_in[1];
  const float* wq   = (const float*)d_in[2];
  const float* bq   = (const float*)d_in[3];
  const float* wk   = (const float*)d_in[4];
  const float* bk   = (const float*)d_in[5];
  const float* wv   = (const float*)d_in[6];
  const float* bv   = (const float*)d_in[7];
  const float* wo   = (const float*)d_in[8];
  const float* bo   = (const float*)d_in[9];
  const float* w1   = (const float*)d_in[10];
  const float* b1   = (const float*)d_in[11];
  const float* w2   = (const float*)d_in[12];
  const float* b2   = (const float*)d_in[13];
  const float* ln1a = (const float*)d_in[14];
  const float* ln1b = (const float*)d_in[15];
  const float* ln2a = (const float*)d_in[16];
  const float* ln2b = (const float*)d_in[17];

  char* ws = (char*)d_ws;
  bf16*  wqkvT = (bf16*) (ws + 0);                 //  6 MB [3072][1024]
  bf16*  woT   = (bf16*) (ws + 6291456);           //  2 MB [1024][1024]
  bf16*  w1T   = (bf16*) (ws + 8388608);           //  8 MB [4096][1024]
  bf16*  w2T   = (bf16*) (ws + 16777216);          //  8 MB [1024][4096]
  float* bqkv  = (float*)(ws + 25165824);          // 12 KB [3072]
  bf16*  xn    = (bf16*) (ws + 25178112);          // 16 MB [8192][1024] (dead after QKV gemm)
  bf16*  vT    = (bf16*) (ws + 25178112);          // 16 MB [64][64][2048], reuses xn slot
  bf16*  qkv   = (bf16*) (ws + 41955328);          // 48 MB [8192][3072]
  bf16*  ctx   = (bf16*) (ws + 92286976);          // 16 MB [8192][1024]
  bf16*  hn    = (bf16*) (ws + 109064192);         // 16 MB [8192][1024]
  bf16*  act   = (bf16*) (ws + 25178112);          // 64 MB [8192][4096], aliases vT+qkv (dead by then)

  PrepArgs pa;
  pa.w[0]=wq; pa.w[1]=wk; pa.w[2]=wv; pa.w[3]=wo; pa.w[4]=w1; pa.w[5]=w2;
  pa.b[0]=bq; pa.b[1]=bk; pa.b[2]=bv;
  prep<<<12289,256,0,stream>>>(pa, wqkvT, w1T, w2T, bqkv);

  // LN1 -> xn
  ln_fwd<<<8192,256,0,stream>>>(x, ln1a, ln1b, xn);
  // QKV projection: [8192,3072]; q-slice scaled by QSCALE in epilogue (EPI=3)
  gemm256<3><<<dim3(32,12),512,0,stream>>>(xn, wqkvT, bqkv, qkv, 3072, 1024);
  // V -> vT[bh][d][s]
  v_transpose<<<dim3(32,64),256,0,stream>>>(qkv, vT);
  // attention -> ctx (MFMA flash, QT=256 per block, 8 waves, 32x32 shapes)
  flash_attn_mfma<<<dim3(S_/256,H_,B_),512,0,stream>>>(qkv, vT, mask, ctx);
  // out projection + residual(x) -> h (stored in d_out, f32): 8-phase 256x128
  gemm256r<<<dim3(32,8),512,0,stream>>>(ctx, woT, bo, x, (float*)d_out, 1024, 1024);
  // LN2 -> hn
  ln_fwd<<<8192,256,0,stream>>>((const float*)d_out, ln2a, ln2b, hn);
  // FFN1 + ReLU -> act
  gemm256<1><<<dim3(32,16),512,0,stream>>>(hn, w1T, b1, act, F_, 1024);
  // FFN2 + residual(h) -> d_out: 8-phase 256x128, K=4096
  gemm256r<<<dim3(32,8),512,0,stream>>>(act, w2T, b2, (const float*)d_out, (float*)d_out, 1024, 4096);
}

// Round 14
// 524.676 us; speedup vs baseline: 1.0095x; 1.0095x over previous
//
#include <hip/hip_runtime.h>
#include <hip/hip_bf16.h>

typedef __attribute__((ext_vector_type(8))) short bf16x8;
typedef __attribute__((ext_vector_type(4))) short bf16x4;
typedef __attribute__((ext_vector_type(4))) float f32x4;
typedef __hip_bfloat16 bf16;
typedef unsigned short u16;

#define B_ 4
#define S_ 2048
#define D_ 1024
#define F_ 4096
#define H_ 16
#define MROWS 8192   // B_*S_
// 1/sqrt(dk) * log2(e), folded into the q-slice of the QKV GEMM epilogue
#define QSCALE 0.18033688011116012f

// ---------------- helpers ----------------
// pack 2 f32 -> 2 bf16 (round-half-up): 2 adds + 1 v_perm
__device__ __forceinline__ unsigned pkbf(float lo, float hi){
  union{float f; unsigned u;} a, b; a.f = lo; b.f = hi;
  return __builtin_amdgcn_perm(b.u + 0x8000u, a.u + 0x8000u, 0x07060302);
}
// single f32 -> bf16 bits (round-half-up): 2 VALU
__device__ __forceinline__ u16 bfrnd(float f){
  union{float ff; unsigned u;} c; c.ff = f;
  return (u16)((c.u + 0x8000u) >> 16);
}
// async global->LDS, 16B per lane; LDS dest = wave-uniform base + lane*16
__device__ __forceinline__ void gll16(const bf16* gp, u16* lp){
  __builtin_amdgcn_global_load_lds(
      (const __attribute__((address_space(1))) void*)gp,
      (__attribute__((address_space(3))) void*)lp, 16, 0, 0);
}

// ---------------- fused prep: 6 weight transposes + bias concat, ONE launch ----------------
// transpose semantics: W[K][N] f32 -> WT[N][K] bf16
struct PrepArgs { const float* w[6]; const float* b[3]; };
__global__ __launch_bounds__(256) void prep(
    PrepArgs pa, bf16* __restrict__ wqkvoT, bf16* __restrict__ w1T,
    bf16* __restrict__ w2T, float* __restrict__ bqkv)
{
  __shared__ float tl[32][33];
  const int bid = blockIdx.x, tid = threadIdx.x;
  const int x = tid&31, y = tid>>5;
  if (bid < 12288) {
    const float* W; bf16* dst; int K, N, nb, kb;
    if (bid < 4096)      { int wi=bid>>10, t=bid&1023; W=pa.w[wi]; dst=wqkvoT+(size_t)wi*1048576; K=1024; N=1024; nb=t&31;  kb=t>>5; }
    else if (bid < 8192) { int t=bid-4096;             W=pa.w[4];  dst=w1T;  K=1024; N=4096; nb=t&127; kb=t>>7; }
    else                 { int t=bid-8192;             W=pa.w[5];  dst=w2T;  K=4096; N=1024; nb=t&31;  kb=t>>5; }
    const int n0=nb*32, k0=kb*32;
    #pragma unroll
    for (int i=0;i<32;i+=8)
      tl[y+i][x] = W[(size_t)(k0+y+i)*N + n0+x];
    __syncthreads();
    #pragma unroll
    for (int i=0;i<32;i+=8)
      dst[(size_t)(n0+y+i)*K + k0+x] = __float2bfloat16(tl[x][y+i]);
  } else {
    for (int i=tid; i<3072; i+=256) bqkv[i] = pa.b[i>>10][i&1023];
  }
}

// ---------------- V transpose: qkv v-slice -> vT[bh][d][s] ----------------
__global__ __launch_bounds__(256) void v_transpose(
    const bf16* __restrict__ qkv, bf16* __restrict__ vT)
{
  __shared__ u16 tile[64*65];   // pitch 65 (odd) spreads banks for the column gather
  const int bh = blockIdx.y, b = bh>>4, h = bh&15;
  const int s0 = blockIdx.x*64;
  const int tid = threadIdx.x;
  const bf16* src = qkv + (size_t)(b*S_ + s0)*3072 + 2048 + h*64;
  #pragma unroll
  for (int i=0;i<2;i++){
    int idx = i*256 + tid;
    int r = idx>>3, sg = idx&7;
    uint4 v = *reinterpret_cast<const uint4*>(src + (size_t)r*3072 + sg*8);
    const u16* e = (const u16*)&v;
    #pragma unroll
    for (int j=0;j<8;j++) tile[r*65 + sg*8 + j] = e[j];
  }
  __syncthreads();
  bf16* dst = vT + (size_t)bh*64*S_ + s0;
  #pragma unroll
  for (int i=0;i<2;i++){
    int idx = i*256 + tid;
    int d = idx>>3, sg = idx&7;
    u16 tmp[8];
    #pragma unroll
    for (int j=0;j<8;j++) tmp[j] = tile[(sg*8+j)*65 + d];
    *reinterpret_cast<uint4*>(dst + (size_t)d*S_ + sg*8) = *reinterpret_cast<uint4*>(tmp);
  }
}

// ---------------- layernorm (torch-faithful: ddof=1, eps added to std) ----------------
__device__ __forceinline__ float block_reduce_256(float v, float* sbuf){
  #pragma unroll
  for (int o=32;o>0;o>>=1) v += __shfl_down(v, o);
  int wave = threadIdx.x>>6;
  if ((threadIdx.x&63)==0) sbuf[wave] = v;
  __syncthreads();
  float r = sbuf[0]+sbuf[1]+sbuf[2]+sbuf[3];
  __syncthreads();
  return r;
}

__global__ __launch_bounds__(256) void ln_fwd(
    const float* __restrict__ x, const float* __restrict__ alpha,
    const float* __restrict__ beta, bf16* __restrict__ out)
{
  __shared__ float sbuf[4];
  int row = blockIdx.x, tid = threadIdx.x;
  const float4* xr = reinterpret_cast<const float4*>(x + (size_t)row*D_);
  float4 v = xr[tid];
  float sum = block_reduce_256(v.x+v.y+v.z+v.w, sbuf);
  float mean = sum * (1.0f/1024.0f);
  float dx0=v.x-mean, dx1=v.y-mean, dx2=v.z-mean, dx3=v.w-mean;
  float ssq = block_reduce_256(dx0*dx0+dx1*dx1+dx2*dx2+dx3*dx3, sbuf);
  float std_ = sqrtf(ssq * (1.0f/1023.0f));        // ddof=1
  float inv = 1.0f/(std_ + 1e-6f);                 // eps added to std
  const float4* ar = reinterpret_cast<const float4*>(alpha);
  const float4* br = reinterpret_cast<const float4*>(beta);
  float4 a = ar[tid], bb = br[tid];
  unsigned* o = reinterpret_cast<unsigned*>(out + (size_t)row*D_);
  o[tid*2+0] = pkbf(a.x*dx0*inv + bb.x, a.y*dx1*inv + bb.y);
  o[tid*2+1] = pkbf(a.z*dx2*inv + bb.z, a.w*dx3*inv + bb.w);
}

// ---------------- GEMM: 512 threads, 128x128 tile, 8 waves of 64x32 (legacy fallback) ----------------
template<int EPI>
__global__ __launch_bounds__(512) void gemm_bt(
    const bf16* __restrict__ A, const bf16* __restrict__ BT,
    const float* __restrict__ bias, const float* __restrict__ res,
    void* __restrict__ out, int M, int N, int K)
{
  __shared__ __align__(16) u16 As[128*32];
  __shared__ __align__(16) u16 Bs[128*32];
  const int tid = threadIdx.x;
  const int m0 = blockIdx.x*128, n0 = blockIdx.y*128;
  const int wave = tid>>6, lane = tid&63;
  const int wm = (wave>>2)*64, wn = (wave&3)*32;
  const int lrow = lane&15, quad = lane>>4;
  const int srow = wave*16 + (lane>>2);
  const int sseg = lane&3;
  const bf16* apg = A  + (size_t)(m0+srow)*K + sseg*8;
  const bf16* bpg = BT + (size_t)(n0+srow)*K + sseg*8;
  u16* asd = &As[wave*512];
  u16* bsd = &Bs[wave*512];

  f32x4 acc[4][2];
  #pragma unroll
  for (int i=0;i<4;i++)
    #pragma unroll
    for (int j=0;j<2;j++) acc[i][j] = (f32x4){0.f,0.f,0.f,0.f};

  for (int k0=0; k0<K; k0+=32) {
    gll16(apg + k0, asd);
    gll16(bpg + k0, bsd);
    __syncthreads();
    bf16x8 a[4], b[2];
    #pragma unroll
    for (int t=0;t<4;t++)
      a[t] = *reinterpret_cast<const bf16x8*>(&As[(wm + t*16 + lrow)*32 + quad*8]);
    #pragma unroll
    for (int t=0;t<2;t++)
      b[t] = *reinterpret_cast<const bf16x8*>(&Bs[(wn + t*16 + lrow)*32 + quad*8]);
    #pragma unroll
    for (int mt=0;mt<4;mt++)
      #pragma unroll
      for (int nt=0;nt<2;nt++)
        acc[mt][nt] = __builtin_amdgcn_mfma_f32_16x16x32_bf16(a[mt], b[nt], acc[mt][nt], 0,0,0);
    __syncthreads();
  }

  #pragma unroll
  for (int mt=0;mt<4;mt++){
    #pragma unroll
    for (int nt=0;nt<2;nt++){
      int col = n0 + wn + nt*16 + lrow;
      float bv = bias[col];
      float sc = (EPI == 3 && col < 1024) ? QSCALE : 1.0f;
      #pragma unroll
      for (int r=0;r<4;r++){
        int row = m0 + wm + mt*16 + quad*4 + r;
        size_t idx = (size_t)row*N + col;
        float val = acc[mt][nt][r] + bv;
        if (EPI == 1) val = fmaxf(val, 0.0f);
        if (EPI == 3) val *= sc;
        if (EPI == 2) {
          ((float*)out)[idx] = val + res[idx];
        } else {
          ((u16*)out)[idx] = bfrnd(val);
        }
      }
    }
  }
}

// ---------------- GEMM 256x256, BK=64, 8-phase pipelined (m201-style template) ----------------
#define LA256(bu,hf) (lds + (((bu)*2+0)*2+(hf))*8192)
#define LB256(bu,hf) (lds + (((bu)*2+1)*2+(hf))*8192)

__device__ __forceinline__ bf16x8 ldfrag(const u16* base, int row, int chunk){
  int pc = chunk ^ (row & 7);                       // T2 swizzle on read
  return *reinterpret_cast<const bf16x8*>(base + row*64 + pc*8);
}

__device__ __forceinline__ void stage_half256(const bf16* __restrict__ src, int K,
                                              u16* lbase, int wave, int lane){
  #pragma unroll
  for (int i=0;i<2;i++){
    int q = i*512 + wave*64 + lane;                 // physical 16B chunk index
    int row = q>>3;
    int seg = (q&7) ^ (row&7);                      // inverse swizzle on global source
    gll16(src + (size_t)row*K + seg*8, lbase + (i*512 + wave*64)*8);
  }
}

template<int RH, int KS, bool RB, typename STG, typename TAIL>
__device__ __forceinline__ void gphase(const u16* pa, const u16* pb, int bcol,
    int lr, int quad, bf16x8 (&b)[4][2], f32x4 (&acc)[8][4], STG stg, TAIL tail)
{
  bf16x8 a_[4];
  #pragma unroll
  for (int ar=0; ar<4; ar++)
    a_[ar] = ldfrag(pa, RH*64 + ar*16 + lr, KS*4 + quad);
  if constexpr (RB){
    #pragma unroll
    for (int cb=0; cb<4; cb++){
      b[cb][0] = ldfrag(pb, bcol + cb*16 + lr, quad);
      b[cb][1] = ldfrag(pb, bcol + cb*16 + lr, 4 + quad);
    }
  }
  stg();
  __builtin_amdgcn_s_barrier();
  asm volatile("s_waitcnt lgkmcnt(0)" ::: "memory");
  __builtin_amdgcn_sched_barrier(0);                // rule #18: keep MFMAs below the wait
  __builtin_amdgcn_s_setprio(1);
  #pragma unroll
  for (int ar=0; ar<4; ar++)
    #pragma unroll
    for (int cb=0; cb<4; cb++)
      acc[RH*4+ar][cb] = __builtin_amdgcn_mfma_f32_16x16x32_bf16(a_[ar], b[cb][KS], acc[RH*4+ar][cb], 0,0,0);
  __builtin_amdgcn_s_setprio(0);
  tail();
  __builtin_amdgcn_s_barrier();
}

// EPI: 1=bf16+ReLU (FFN1), 3=bf16 with cols<1024 scaled by QSCALE (QKV). M fixed = MROWS.
template<int EPI>
__global__ __launch_bounds__(512) void gemm256(
    const bf16* __restrict__ A, const bf16* __restrict__ BT,
    const float* __restrict__ bias, bf16* __restrict__ out, int N, int K)
{
  __shared__ __align__(16) u16 lds[65536];          // 131072 B static (gfx950: 160 KiB LDS)
  const int tid = threadIdx.x, wave = tid>>6, lane = tid&63;
  const int wr = wave>>2, wc = wave&3;              // 2M x 4N wave grid
  const int lr = lane&15, quad = lane>>4;
  const int gx = gridDim.x;
  const int nwg = gx*gridDim.y;
  int flat = blockIdx.y*gx + blockIdx.x;
  int cpx = nwg>>3;
  int swz = (flat&7)*cpx + (flat>>3);
  const int m0 = (swz % gx)*256, n0 = (swz / gx)*256;
  const int T = K>>6;

  const bf16* Ag = A  + (size_t)m0*K;
  const bf16* Bg = BT + (size_t)n0*K;
  const int bcol = (wc&1)*64;

  f32x4 acc[8][4];
  #pragma unroll
  for (int i=0;i<8;i++)
    #pragma unroll
    for (int j=0;j<4;j++) acc[i][j] = (f32x4){0.f,0.f,0.f,0.f};

  // prologue: tile0 (4 halves) + B halves of tile1; allow B(1) in flight
  stage_half256(Ag,                       K, LA256(0,0), wave, lane);
  stage_half256(Ag + (size_t)128*K,       K, LA256(0,1), wave, lane);
  stage_half256(Bg,                       K, LB256(0,0), wave, lane);
  stage_half256(Bg + (size_t)128*K,       K, LB256(0,1), wave, lane);
  stage_half256(Bg + 64,                  K, LB256(1,0), wave, lane);
  stage_half256(Bg + (size_t)128*K + 64,  K, LB256(1,1), wave, lane);
  asm volatile("s_waitcnt vmcnt(4)" ::: "memory");
  __builtin_amdgcn_s_barrier();

  for (int t=0; t<T; ++t){
    const int bu = t&1, nbu = bu^1;
    const u16* pa = LA256(bu, wr);
    const u16* pb = LB256(bu, wc>>1);
    const size_t ktA = (size_t)((t+1 < T) ? t+1 : T-1)*64;   // clamp keeps vmcnt counts uniform
    const size_t ktB = (size_t)((t+2 < T) ? t+2 : T-1)*64;
    bf16x8 b[4][2];
    gphase<0,0,true >(pa, pb, bcol, lr, quad, b, acc,
        [&]{ stage_half256(Ag + ktA,                 K, LA256(nbu,0), wave, lane); }, [&]{});
    gphase<1,0,false>(pa, pb, bcol, lr, quad, b, acc,
        [&]{ stage_half256(Ag + (size_t)128*K + ktA, K, LA256(nbu,1), wave, lane); }, [&]{});
    gphase<0,1,false>(pa, pb, bcol, lr, quad, b, acc,
        [&]{ stage_half256(Bg + ktB,                 K, LB256(bu,0),  wave, lane); }, [&]{});
    gphase<1,1,false>(pa, pb, bcol, lr, quad, b, acc,
        [&]{ stage_half256(Bg + (size_t)128*K + ktB, K, LB256(bu,1),  wave, lane); },
        [&]{ asm volatile("s_waitcnt vmcnt(4)" ::: "memory"); });
  }

  // epilogue
  #pragma unroll
  for (int mi=0; mi<8; mi++){
    const int row0 = m0 + wr*128 + (mi>>2)*64 + (mi&3)*16 + quad*4;
    #pragma unroll
    for (int cb=0; cb<4; cb++){
      const int col = n0 + wc*64 + cb*16 + lr;
      float bv = bias[col];
      float sc = (EPI==3 && col < 1024) ? QSCALE : 1.0f;
      #pragma unroll
      for (int r=0; r<4; r++){
        float val = acc[mi][cb][r] + bv;
        if (EPI == 1) val = fmaxf(val, 0.0f);
        if (EPI == 3) val *= sc;
        ((u16*)out)[(size_t)(row0+r)*N + col] = bfrnd(val);
      }
    }
  }
}

// ---------------- GEMM 256x128, BK=64, 8-phase, f32+residual epilogue (Wo / FFN2) ----------------
#define LA2(bu,hf) (lds2 + ((bu)*3+(hf))*8192)
#define LB2(bu)    (lds2 + ((bu)*3+2)*8192)

template<int RH, int KS, bool RB, typename STG, typename TAIL>
__device__ __forceinline__ void gphase2(const u16* pa, const u16* pb, int bcol,
    int lr, int quad, bf16x8 (&b)[2][2], f32x4 (&acc)[8][2], STG stg, TAIL tail)
{
  bf16x8 a_[4];
  #pragma unroll
  for (int ar=0; ar<4; ar++)
    a_[ar] = ldfrag(pa, RH*64 + ar*16 + lr, KS*4 + quad);
  if constexpr (RB){
    #pragma unroll
    for (int cb=0; cb<2; cb++){
      b[cb][0] = ldfrag(pb, bcol + cb*16 + lr, quad);
      b[cb][1] = ldfrag(pb, bcol + cb*16 + lr, 4 + quad);
    }
  }
  stg();
  __builtin_amdgcn_s_barrier();
  asm volatile("s_waitcnt lgkmcnt(0)" ::: "memory");
  __builtin_amdgcn_sched_barrier(0);
  __builtin_amdgcn_s_setprio(1);
  #pragma unroll
  for (int ar=0; ar<4; ar++)
    #pragma unroll
    for (int cb=0; cb<2; cb++)
      acc[RH*4+ar][cb] = __builtin_amdgcn_mfma_f32_16x16x32_bf16(a_[ar], b[cb][KS], acc[RH*4+ar][cb], 0,0,0);
  __builtin_amdgcn_s_setprio(0);
  tail();
  __builtin_amdgcn_s_barrier();
}

__global__ __launch_bounds__(512) void gemm256r(
    const bf16* __restrict__ A, const bf16* __restrict__ BT,
    const float* __restrict__ bias, const float* __restrict__ res,
    float* __restrict__ out, int N, int K)
{
  __shared__ __align__(16) u16 lds2[49152];         // 96 KiB static
  const int tid = threadIdx.x, wave = tid>>6, lane = tid&63;
  const int wr = wave>>2, wc = wave&3;              // 2M x 4N wave grid
  const int lr = lane&15, quad = lane>>4;
  const int gx = gridDim.x;
  const int nwg = gx*gridDim.y;
  int flat = blockIdx.y*gx + blockIdx.x;
  int cpx = nwg>>3;
  int swz = (flat&7)*cpx + (flat>>3);
  const int m0 = (swz % gx)*256, n0 = (swz / gx)*128;
  const int T = K>>6;

  const bf16* Ag = A  + (size_t)m0*K;
  const bf16* Bg = BT + (size_t)n0*K;
  const int bcol = wc*32;

  f32x4 acc[8][2];
  #pragma unroll
  for (int i=0;i<8;i++)
    #pragma unroll
    for (int j=0;j<2;j++) acc[i][j] = (f32x4){0.f,0.f,0.f,0.f};

  // prologue: A(0) both halves, B(0), B(1); leave B(1) in flight
  stage_half256(Ag,                 K, LA2(0,0), wave, lane);
  stage_half256(Ag + (size_t)128*K, K, LA2(0,1), wave, lane);
  stage_half256(Bg,                 K, LB2(0),   wave, lane);
  stage_half256(Bg + 64,            K, LB2(1),   wave, lane);
  asm volatile("s_waitcnt vmcnt(2)" ::: "memory");
  __builtin_amdgcn_s_barrier();

  for (int t=0; t<T; ++t){
    const int bu = t&1, nbu = bu^1;
    const u16* pa = LA2(bu, wr);
    const u16* pb = LB2(bu);
    const size_t ktA = (size_t)((t+1 < T) ? t+1 : T-1)*64;
    const size_t ktB = (size_t)((t+2 < T) ? t+2 : T-1)*64;
    bf16x8 b[2][2];
    gphase2<0,0,true >(pa, pb, bcol, lr, quad, b, acc,
        [&]{ stage_half256(Ag + ktA,                 K, LA2(nbu,0), wave, lane); }, [&]{});
    gphase2<1,0,false>(pa, pb, bcol, lr, quad, b, acc,
        [&]{ stage_half256(Ag + (size_t)128*K + ktA, K, LA2(nbu,1), wave, lane); }, [&]{});
    gphase2<0,1,false>(pa, pb, bcol, lr, quad, b, acc,
        [&]{ stage_half256(Bg + ktB,                 K, LB2(bu),    wave, lane); }, [&]{});
    gphase2<1,1,false>(pa, pb, bcol, lr, quad, b, acc,
        [&]{}, [&]{ asm volatile("s_waitcnt vmcnt(2)" ::: "memory"); });
  }

  // epilogue: f32 + bias + residual
  #pragma unroll
  for (int mi=0; mi<8; mi++){
    const int row0 = m0 + wr*128 + (mi>>2)*64 + (mi&3)*16 + quad*4;
    #pragma unroll
    for (int cb=0; cb<2; cb++){
      const int col = n0 + bcol + cb*16 + lr;
      float bv = bias[col];
      #pragma unroll
      for (int r=0; r<4; r++){
        size_t idx = (size_t)(row0+r)*N + col;
        out[idx] = acc[mi][cb][r] + bv + res[idx];
      }
    }
  }
}

// ---------------- MFMA flash attention: S^T trick, QT=256, 8 waves ----------------
// Round-0 compute (measured 106.4 us) + T14 issue-early double-buffered staging:
// per tile, next K/V rows are global-loaded into regs BEFORE compute (latency hides
// under the ~16-MFMA+softmax phase), written to the OTHER LDS buffer after compute,
// ONE barrier per tile (was 2). Race-free: writes at tile t target buffer ti^1, whose
// last readers (tile t-1) all passed the t-1 end barrier. Mask prefetched (mcur/mnext).
// 32x32-rewrite lesson (round 8): kernel is NOT MFMA-bound (halving MFMA cycles did
// nothing) and bank conflicts are fully hidden (removing all 1.26e7 changed nothing).
#define KP 72   // LDS pitch: 144B rows, 16B-aligned for b128

__global__ __launch_bounds__(512) void flash_attn_mfma(
    const bf16* __restrict__ qkv, const bf16* __restrict__ vT,
    const int* __restrict__ mask, bf16* __restrict__ ctx)
{
  __shared__ __align__(16) u16 Ks[2][64*KP];    // K[key][d], double-buffered
  __shared__ __align__(16) u16 Vt[2][64*KP];    // V^T[d][key], double-buffered
  __shared__ __align__(16) float Mb[2][64];     // mask bias (slow path only)

  const int b = blockIdx.z, h = blockIdx.y, qt = blockIdx.x;
  const int tid = threadIdx.x, wave = tid>>6, lane = tid&63;
  const int lr = lane&15, quad = lane>>4;
  const int qbase = qt*256 + wave*32;           // 32 q-rows per wave (2 q-sets of 16)

  const bf16* base = qkv + (size_t)b*S_*3072 + h*64;
  const bf16* vtb  = vT + (size_t)(b*H_+h)*64*S_;
  const int*  mrow = mask + b*S_;

  bf16x8 qf[2][2];
  #pragma unroll
  for (int c=0;c<2;c++){
    const bf16* qp = base + (size_t)(qbase + c*16 + lr)*3072 + quad*8;
    qf[c][0] = *reinterpret_cast<const bf16x8*>(qp);
    qf[c][1] = *reinterpret_cast<const bf16x8*>(qp + 32);
  }

  const bf16x4 ones4 = {(short)0x3F80,(short)0x3F80,(short)0x3F80,(short)0x3F80};

  f32x4 actx[2][4];                              // [c][dt] : ctx^T[d=dt*16+quad*4+r][q=c*16+lr]
  f32x4 acc_l[2];                                // l per q (rows identical)
  #pragma unroll
  for (int c=0;c<2;c++){
    #pragma unroll
    for (int dt=0;dt<4;dt++) actx[c][dt] = (f32x4){0.f,0.f,0.f,0.f};
    acc_l[c] = (f32x4){0.f,0.f,0.f,0.f};
  }

  const int sr = tid>>3, sg = tid&7;
  const bf16* kgp = base + 1024 + (size_t)sr*3072 + sg*8;   // K row sr, this tile's kt added per use
  const bf16* vgp = vtb + (size_t)sr*S_ + sg*8;

  // ---- prologue: stage tile 0 into buffer 0 ----
  {
    uint4 k0 = *reinterpret_cast<const uint4*>(kgp);
    uint4 v0 = *reinterpret_cast<const uint4*>(vgp);
    *reinterpret_cast<uint4*>(&Ks[0][sr*KP + sg*8]) = k0;
    *reinterpret_cast<uint4*>(&Vt[0][sr*KP + sg*8]) = v0;
  }
  int mcur = mrow[lane];
  if (tid < 64) Mb[0][tid] = (mcur==0) ? -2e9f : 0.0f;
  __syncthreads();

  int ti = 0;
  for (int kt=0; kt<S_; kt+=64, ti^=1){
    const bool more = (kt+64 < S_);
    // ---- T14: issue next tile's loads BEFORE compute (latency hides under MFMAs) ----
    uint4 kreg, vreg; int mnext = 1;
    if (more){
      kreg = *reinterpret_cast<const uint4*>(kgp + (size_t)(kt+64)*3072);
      vreg = *reinterpret_cast<const uint4*>(vgp + kt + 64);
      mnext = mrow[kt + 64 + lane];
    }
    unsigned long long bal = __ballot(mcur == 0);

    // ---- S^T = K Q^T (q pre-scaled), p = exp2(s), pack to PV B-frags via v_perm ----
    bf16x4 pk[2][4];                             // [c][nt] : keys nt*16+quad*4+j, q=c*16+lr
    if (bal == 0ULL) {
      #pragma unroll
      for (int nt=0;nt<4;nt++){
        bf16x8 kf0 = *reinterpret_cast<const bf16x8*>(&Ks[ti][(nt*16+lr)*KP + quad*8]);
        bf16x8 kf1 = *reinterpret_cast<const bf16x8*>(&Ks[ti][(nt*16+lr)*KP + 32 + quad*8]);
        #pragma unroll
        for (int c=0;c<2;c++){
          f32x4 a = (f32x4){0.f,0.f,0.f,0.f};
          a = __builtin_amdgcn_mfma_f32_16x16x32_bf16(kf0, qf[c][0], a, 0,0,0);
          a = __builtin_amdgcn_mfma_f32_16x16x32_bf16(kf1, qf[c][1], a, 0,0,0);
          uint2 w;
          w.x = pkbf(__builtin_amdgcn_exp2f(a[0]), __builtin_amdgcn_exp2f(a[1]));
          w.y = pkbf(__builtin_amdgcn_exp2f(a[2]), __builtin_amdgcn_exp2f(a[3]));
          union{uint2 u; bf16x4 v;} cvt; cvt.u = w;
          pk[c][nt] = cvt.v;
        }
      }
    } else {
      #pragma unroll
      for (int nt=0;nt<4;nt++){
        bf16x8 kf0 = *reinterpret_cast<const bf16x8*>(&Ks[ti][(nt*16+lr)*KP + quad*8]);
        bf16x8 kf1 = *reinterpret_cast<const bf16x8*>(&Ks[ti][(nt*16+lr)*KP + 32 + quad*8]);
        float4 mb = *reinterpret_cast<const float4*>(&Mb[ti][nt*16 + quad*4]);
        #pragma unroll
        for (int c=0;c<2;c++){
          f32x4 a = (f32x4){0.f,0.f,0.f,0.f};
          a = __builtin_amdgcn_mfma_f32_16x16x32_bf16(kf0, qf[c][0], a, 0,0,0);
          a = __builtin_amdgcn_mfma_f32_16x16x32_bf16(kf1, qf[c][1], a, 0,0,0);
          uint2 w;
          w.x = pkbf(__builtin_amdgcn_exp2f(a[0]+mb.x), __builtin_amdgcn_exp2f(a[1]+mb.y));
          w.y = pkbf(__builtin_amdgcn_exp2f(a[2]+mb.z), __builtin_amdgcn_exp2f(a[3]+mb.w));
          union{uint2 u; bf16x4 v;} cvt; cvt.u = w;
          pk[c][nt] = cvt.v;
        }
      }
    }

    // ---- ctx^T += V^T P^T ; l += 1^T P (both on MFMA pipe) ----
    #pragma unroll
    for (int dt=0;dt<4;dt++){
      #pragma unroll
      for (int kc=0;kc<4;kc++){
        bf16x4 vf = *reinterpret_cast<const bf16x4*>(&Vt[ti][(dt*16+lr)*KP + kc*16 + quad*4]);
        #pragma unroll
        for (int c=0;c<2;c++)
          actx[c][dt] = __builtin_amdgcn_mfma_f32_16x16x16bf16_1k(vf, pk[c][kc], actx[c][dt], 0,0,0);
      }
    }
    #pragma unroll
    for (int kc=0;kc<4;kc++)
      #pragma unroll
      for (int c=0;c<2;c++)
        acc_l[c] = __builtin_amdgcn_mfma_f32_16x16x16bf16_1k(ones4, pk[c][kc], acc_l[c], 0,0,0);

    // ---- write prefetched tile to the other buffer (compiler waits vmcnt here) ----
    if (more){
      *reinterpret_cast<uint4*>(&Ks[ti^1][sr*KP + sg*8]) = kreg;
      *reinterpret_cast<uint4*>(&Vt[ti^1][sr*KP + sg*8]) = vreg;
      if (tid < 64) Mb[ti^1][tid] = (mnext==0) ? -2e9f : 0.0f;
    }
    mcur = mnext;
    __syncthreads();
  }

  // ---- epilogue: l is complete per lane (no shuffles), normalize, b64 stores ----
  #pragma unroll
  for (int c=0;c<2;c++){
    float inv = 1.0f/acc_l[c][0];
    int q = qbase + c*16 + lr;
    bf16* op = ctx + (size_t)(b*S_+q)*D_ + h*64 + quad*4;
    #pragma unroll
    for (int dt=0;dt<4;dt++){
      uint2 o;
      o.x = pkbf(actx[c][dt][0]*inv, actx[c][dt][1]*inv);
      o.y = pkbf(actx[c][dt][2]*inv, actx[c][dt][3]*inv);
      *reinterpret_cast<uint2*>(op + dt*16) = o;
    }
  }
}

// ---------------- launch ----------------
extern "C" void kernel_launch(void* const* d_in, const int* in_sizes, int n_in,
                              void* d_out, int out_size, void* d_ws, size_t ws_size,
                              hipStream_t stream) {
  const float* x    = (const float*)d_in[0];
  const int*   mask = (const int*)  d_in[1];
  const float* wq   = (const float*)d_in[2];
  const float* bq   = (const float*)d_in[3];
  const float* wk   = (const float*)d_in[4];
  const float* bk   = (const float*)d_in[5];
  const float* wv   = (const float*)d_in[6];
  const float* bv   = (const float*)d_in[7];
  const float* wo   = (const float*)d_in[8];
  const float* bo   = (const float*)d_in[9];
  const float* w1   = (const float*)d_in[10];
  const float* b1   = (const float*)d_in[11];
  const float* w2   = (const float*)d_in[12];
  const float* b2   = (const float*)d_in[13];
  const float* ln1a = (const float*)d_in[14];
  const float* ln1b = (const float*)d_in[15];
  const float* ln2a = (const float*)d_in[16];
  const float* ln2b = (const float*)d_in[17];

  char* ws = (char*)d_ws;
  bf16*  wqkvT = (bf16*) (ws + 0);                 //  6 MB [3072][1024]
  bf16*  woT   = (bf16*) (ws + 6291456);           //  2 MB [1024][1024]
  bf16*  w1T   = (bf16*) (ws + 8388608);           //  8 MB [4096][1024]
  bf16*  w2T   = (bf16*) (ws + 16777216);          //  8 MB [1024][4096]
  float* bqkv  = (float*)(ws + 25165824);          // 12 KB [3072]
  bf16*  xn    = (bf16*) (ws + 25178112);          // 16 MB [8192][1024] (dead after QKV gemm)
  bf16*  vT    = (bf16*) (ws + 25178112);          // 16 MB [64][64][2048], reuses xn slot
  bf16*  qkv   = (bf16*) (ws + 41955328);          // 48 MB [8192][3072]
  bf16*  ctx   = (bf16*) (ws + 92286976);          // 16 MB [8192][1024]
  bf16*  hn    = (bf16*) (ws + 109064192);         // 16 MB [8192][1024]
  bf16*  act   = (bf16*) (ws + 25178112);          // 64 MB [8192][4096], aliases vT+qkv (dead by then)

  PrepArgs pa;
  pa.w[0]=wq; pa.w[1]=wk; pa.w[2]=wv; pa.w[3]=wo; pa.w[4]=w1; pa.w[5]=w2;
  pa.b[0]=bq; pa.b[1]=bk; pa.b[2]=bv;
  prep<<<12289,256,0,stream>>>(pa, wqkvT, w1T, w2T, bqkv);

  // LN1 -> xn
  ln_fwd<<<8192,256,0,stream>>>(x, ln1a, ln1b, xn);
  // QKV projection: [8192,3072]; q-slice scaled by QSCALE in epilogue (EPI=3)
  gemm256<3><<<dim3(32,12),512,0,stream>>>(xn, wqkvT, bqkv, qkv, 3072, 1024);
  // V -> vT[bh][d][s]
  v_transpose<<<dim3(32,64),256,0,stream>>>(qkv, vT);
  // attention -> ctx (MFMA flash, QT=256 per block, 8 waves, T14 dbuf staging)
  flash_attn_mfma<<<dim3(S_/256,H_,B_),512,0,stream>>>(qkv, vT, mask, ctx);
  // out projection + residual(x) -> h (stored in d_out, f32): 8-phase 256x128
  gemm256r<<<dim3(32,8),512,0,stream>>>(ctx, woT, bo, x, (float*)d_out, 1024, 1024);
  // LN2 -> hn
  ln_fwd<<<8192,256,0,stream>>>((const float*)d_out, ln2a, ln2b, hn);
  // FFN1 + ReLU -> act
  gemm256<1><<<dim3(32,16),512,0,stream>>>(hn, w1T, b1, act, F_, 1024);
  // FFN2 + residual(h) -> d_out: 8-phase 256x128, K=4096
  gemm256r<<<dim3(32,8),512,0,stream>>>(act, w2T, b2, (const float*)d_out, (float*)d_out, 1024, 4096);
}